// Round 7
// baseline (167.146 us; speedup 1.0000x reference)
//
#include <hip/hip_runtime.h>
#include <hip/hip_bf16.h>

#define B_ 16
#define P_ 1024
#define T_ (B_*P_)
#define CH_ 32          // chunks per batch for the softmax scan
#define CL_ (P_/CH_)    // 32 positions per chunk

// ---- ws layout (floats). Weights staged to f32; token inputs read raw. ----
constexpr int OFF_A     = 16;                       // 95*4 + 4 = 384
constexpr int OFF_WPSI1 = 400;                      // 1984
constexpr int OFF_BPSI1 = OFF_WPSI1 + 1984;         // 64
constexpr int OFF_WPSI2 = OFF_BPSI1 + 64;           // 4096
constexpr int OFF_BPSI2 = OFF_WPSI2 + 4096;         // 64
constexpr int OFF_WPHI1 = OFF_BPSI2 + 64;           // 992
constexpr int OFF_BPHI1 = OFF_WPHI1 + 992;          // 32
constexpr int OFF_WPHI2 = OFF_BPHI1 + 32;           // 1024
constexpr int OFF_BPHI2 = OFF_WPHI2 + 1024;         // 32
constexpr int OFF_WRHO1 = OFF_BPHI2 + 32;           // 8192
constexpr int OFF_BRHO1 = OFF_WRHO1 + 8192;         // 64
constexpr int OFF_WRHO2 = OFF_BRHO1 + 64;           // 4096
constexpr int OFF_BRHO2 = OFF_WRHO2 + 4096;         // 64
constexpr int OFF_PHI   = OFF_BRHO2 + 64;           // T*32
constexpr int OFF_Z     = OFF_PHI   + T_*32;        // T*4
constexpr int OFF_PREX  = OFF_Z     + T_*4;         // T*4
constexpr int OFF_PRE   = OFF_PREX  + T_*4;         // T*4
constexpr int OFF_CME   = OFF_PRE   + T_*4;         // B*CH*4*2 = 4096
constexpr int OFF_CS    = OFF_CME   + 4096;         // B*CH*4*32 = 65536

static __device__ __forceinline__ bool detect_f32(const void* mask_raw) {
  return ((*(const unsigned*)mask_raw) & 0xFFFFu) == 0u;
}
static __device__ __forceinline__ float ld_any(const void* src, int i, bool isf32) {
  if (isf32) return ((const float*)src)[i];
  return __bfloat162float(((const __hip_bfloat16*)src)[i]);
}

// ---------- S01: stage weights to f32 (blocks >=2) + fold A (blocks 0..1) ----------
__global__ __launch_bounds__(256) void s01_prep(
    float* __restrict__ ws, const void* mask,
    const void* Wpsi1, const void* bpsi1, const void* Wpsi2, const void* bpsi2,
    const void* Wkey,  const void* bkey,  const void* query,
    const void* Wphi1, const void* bphi1, const void* Wphi2, const void* bphi2,
    const void* Wrho1, const void* brho1, const void* Wrho2, const void* brho2) {
  const bool isf32 = detect_f32(mask);
  if (blockIdx.x < 2) {
    const int gid = blockIdx.x * 256 + threadIdx.x;
    if (gid >= 384) return;
    const float inv_s = 0.17677669529663687f;
    const int h = gid & 3;
    const int j = gid >> 2;  // 0..95; 95 = bias row
    float s = 0.f;
    if (j < 95) {
      for (int d = 0; d < 32; ++d)
        s += ld_any(Wkey, j * 128 + h * 32 + d, isf32) * ld_any(query, h * 32 + d, isf32);
    } else {
      for (int d = 0; d < 32; ++d)
        s += ld_any(bkey, h * 32 + d, isf32) * ld_any(query, h * 32 + d, isf32);
    }
    ws[OFF_A + gid] = s * inv_s;  // A[j][h] at j*4+h; c0[h] at 380+h
    return;
  }
  const int g  = (blockIdx.x - 2) * 256 + threadIdx.x;
  const int gs = (gridDim.x - 2) * 256;
  auto st = [&](int off, const void* src, int n) {
    for (int i = g; i < n; i += gs) ws[off + i] = ld_any(src, i, isf32);
  };
  st(OFF_WPSI1, Wpsi1, 1984); st(OFF_BPSI1, bpsi1, 64);
  st(OFF_WPSI2, Wpsi2, 4096); st(OFF_BPSI2, bpsi2, 64);
  st(OFF_WPHI1, Wphi1, 992);  st(OFF_BPHI1, bphi1, 32);
  st(OFF_WPHI2, Wphi2, 1024); st(OFF_BPHI2, bphi2, 32);
  st(OFF_WRHO1, Wrho1, 8192); st(OFF_BRHO1, brho1, 64);
  st(OFF_WRHO2, Wrho2, 4096); st(OFF_BRHO2, brho2, 64);
}

// ---------- K1: wave-per-token MLPs. 4 tokens/block, lane=channel ----------
__global__ __launch_bounds__(256) void k1_token(float* __restrict__ ws,
                                                const int* __restrict__ measp,
                                                const void* __restrict__ times,
                                                const void* __restrict__ values,
                                                const void* __restrict__ mask) {
  __shared__ float sh1[4][64];
  __shared__ float sg1[4][32];
  const bool isf32 = detect_f32(mask);
  const int tid = threadIdx.x;
  const int wv  = __builtin_amdgcn_readfirstlane(tid >> 6);
  const int j   = tid & 63;
  const int t   = blockIdx.x * 4 + wv;

  const float tval = ld_any(times, t, isf32);
  const float vval = ld_any(values, t, isf32);
  const float mval = ld_any(mask, t, isf32);
  const int   meas = measp[t];
  const float sel  = (meas > 0) ? 1.f : 0.f;
  const int   mrow = (meas > 0) ? (8 + meas) : 0;

  float x[9];
  const float posv[4] = {1.f, 10.f, 100.f, 1000.f};
  #pragma unroll
  for (int k = 0; k < 4; ++k) {
    float s, c;
    __sincosf(tval / posv[k], &s, &c);
    x[2*k] = s; x[2*k+1] = c;
  }
  x[8] = vval;

  // psi L1, channel j
  float h1 = ws[OFF_BPSI1 + j];
  #pragma unroll
  for (int i = 0; i < 9; ++i) h1 = fmaf(x[i], ws[OFF_WPSI1 + i * 64 + j], h1);
  h1 = fmaf(sel, ws[OFF_WPSI1 + mrow * 64 + j], h1);
  sh1[wv][j] = fmaxf(h1, 0.f);

  // phi L1, lanes 0..31
  if (j < 32) {
    float g1 = ws[OFF_BPHI1 + j];
    #pragma unroll
    for (int i = 0; i < 9; ++i) g1 = fmaf(x[i], ws[OFF_WPHI1 + i * 32 + j], g1);
    g1 = fmaf(sel, ws[OFF_WPHI1 + mrow * 32 + j], g1);
    sg1[wv][j] = fmaxf(g1, 0.f);
  }
  __syncthreads();

  // psi L2
  float h2 = ws[OFF_BPSI2 + j];
  #pragma unroll 8
  for (int i = 0; i < 64; ++i) h2 = fmaf(sh1[wv][i], ws[OFF_WPSI2 + i * 64 + j], h2);
  const float q = fmaxf(h2, 0.f) * mval;

  // z[h] = sum_j q_j * A2[j][h] — butterfly over the wave
  const float* a2 = ws + OFF_A + (31 + j) * 4;
  float z0 = q * a2[0], z1 = q * a2[1], z2 = q * a2[2], z3 = q * a2[3];
  #pragma unroll
  for (int off = 32; off; off >>= 1) {
    z0 += __shfl_xor(z0, off, 64);
    z1 += __shfl_xor(z1, off, 64);
    z2 += __shfl_xor(z2, off, 64);
    z3 += __shfl_xor(z3, off, 64);
  }
  if (j == 0) {
    float* zo = ws + OFF_Z + (size_t)t * 4;
    zo[0] = z0; zo[1] = z1; zo[2] = z2; zo[3] = z3;
  }

  // phi L2 on lanes 0..31; pre_x on lanes 32..35
  if (j < 32) {
    float g2 = ws[OFF_BPHI2 + j];
    #pragma unroll 8
    for (int i = 0; i < 32; ++i) g2 = fmaf(sg1[wv][i], ws[OFF_WPHI2 + i * 32 + j], g2);
    ws[OFF_PHI + (size_t)t * 32 + j] = fmaxf(g2, 0.f) * mval;
  } else if (j < 36) {
    const int h = j - 32;
    float pr = ws[OFF_A + 380 + h];
    #pragma unroll
    for (int i = 0; i < 9; ++i) pr = fmaf(x[i], ws[OFF_A + i * 4 + h], pr);
    pr = fmaf(sel, ws[OFF_A + mrow * 4 + h], pr);
    ws[OFF_PREX + (size_t)t * 4 + h] = pr;
  }
}

// ---------- K2: block-parallel scan of (cnt, z[4]) -> pre; 1 block/batch ----------
__global__ __launch_bounds__(256) void k2_scanz(float* __restrict__ ws,
                                                const void* __restrict__ mask) {
  const int b   = blockIdx.x;
  const int tid = threadIdx.x;
  const bool isf32 = detect_f32(mask);
  __shared__ float sc[256], s0[256], s1[256], s2[256], s3[256];

  const float* zB = ws + OFF_Z + (size_t)b * P_ * 4;
  const int p0 = tid * 4;

  float lc[4], l0[4], l1[4], l2[4], l3[4];
  float c = 0.f, z0 = 0.f, z1 = 0.f, z2 = 0.f, z3 = 0.f;
  #pragma unroll
  for (int i = 0; i < 4; ++i) {
    c  += ld_any(mask, b * P_ + p0 + i, isf32);
    z0 += zB[(p0 + i) * 4 + 0]; z1 += zB[(p0 + i) * 4 + 1];
    z2 += zB[(p0 + i) * 4 + 2]; z3 += zB[(p0 + i) * 4 + 3];
    lc[i] = c; l0[i] = z0; l1[i] = z1; l2[i] = z2; l3[i] = z3;
  }

  float rc = c, r0 = z0, r1 = z1, r2 = z2, r3 = z3;
  sc[tid] = rc; s0[tid] = r0; s1[tid] = r1; s2[tid] = r2; s3[tid] = r3;
  __syncthreads();
  for (int off = 1; off < 256; off <<= 1) {
    float ac = 0.f, a0 = 0.f, a1 = 0.f, a2 = 0.f, a3 = 0.f;
    if (tid >= off) {
      ac = sc[tid - off]; a0 = s0[tid - off]; a1 = s1[tid - off];
      a2 = s2[tid - off]; a3 = s3[tid - off];
    }
    __syncthreads();
    rc += ac; r0 += a0; r1 += a1; r2 += a2; r3 += a3;
    sc[tid] = rc; s0[tid] = r0; s1[tid] = r1; s2[tid] = r2; s3[tid] = r3;
    __syncthreads();
  }
  const float ec = rc - c, e0 = r0 - z0, e1 = r1 - z1, e2 = r2 - z2, e3 = r3 - z3;

  const float* px  = ws + OFF_PREX + (size_t)b * P_ * 4;
  float*       pre = ws + OFF_PRE  + (size_t)b * P_ * 4;
  #pragma unroll
  for (int i = 0; i < 4; ++i) {
    const float inv = 1.f / (ec + lc[i]);
    const int p = p0 + i;
    pre[p * 4 + 0] = px[p * 4 + 0] + (e0 + l0[i]) * inv;
    pre[p * 4 + 1] = px[p * 4 + 1] + (e1 + l1[i]) * inv;
    pre[p * 4 + 2] = px[p * 4 + 2] + (e2 + l2[i]) * inv;
    pre[p * 4 + 3] = px[p * 4 + 3] + (e3 + l3[i]) * inv;
  }
}

// ---------- K4a: per-chunk softmax-state reduction (CL=32) ----------
__global__ __launch_bounds__(128) void k4a_chunk(float* __restrict__ ws) {
  const int ch = blockIdx.x, b = blockIdx.y;
  const int h = threadIdx.x >> 5, d = threadIdx.x & 31;
  const float* preB = ws + OFF_PRE + (size_t)b * P_ * 4;
  const float* phiB = ws + OFF_PHI + (size_t)b * P_ * 32;

  float M = -__builtin_inff(), E = 0.f, S = 0.f;
  const int pbeg = ch * CL_;
  for (int p = pbeg; p < pbeg + CL_; ++p) {
    const float v  = preB[p * 4 + h];
    const float ph = phiB[p * 32 + d];
    const float nM = fmaxf(M, v);
    const float al = __expf(M - nM);
    const float w  = __expf(v - nM);
    E = fmaf(E, al, w);
    S = fmaf(S, al, w * ph);
    M = nM;
  }
  const int base = (b * CH_ + ch) * 4 + h;
  if (d == 0) { ws[OFF_CME + base * 2] = M; ws[OFF_CME + base * 2 + 1] = E; }
  ws[OFF_CS + base * 32 + d] = S;
}

// ---------- K4R: prefix combine + replay into LDS + fused rho MLP ----------
// grid (CH_, B_), 128 threads. Phase A: lane=(h,d). Phase B: wave w, lane=out-channel j.
__global__ __launch_bounds__(128) void k4r_fused(float* __restrict__ ws,
                                                 const void* __restrict__ mask,
                                                 void* __restrict__ out) {
  __shared__ float sAgg[CL_][128];   // 16 KB, [pos][channel]
  __shared__ float sW1[128 * 64];    // 32 KB
  __shared__ float sH1[2][4][64];    // 2 KB, per-wave slots
  const int ch = blockIdx.x, b = blockIdx.y;
  const int tid = threadIdx.x;
  const bool isf32 = detect_f32(mask);

  // stage W_rho1 (f32 in ws) -> LDS as float4
  {
    const float4* src = (const float4*)(ws + OFF_WRHO1);
    float4* dst = (float4*)sW1;
    #pragma unroll
    for (int k = 0; k < 16; ++k) dst[tid + k * 128] = src[tid + k * 128];
  }

  // ---- phase A: softmax prefix + replay chunk into sAgg ----
  {
    const int h = tid >> 5, d = tid & 31;
    const float* preB = ws + OFF_PRE + (size_t)b * P_ * 4;
    const float* phiB = ws + OFF_PHI + (size_t)b * P_ * 32;

    float M = -__builtin_inff(), E = 0.f, S = 0.f;
    for (int c2 = 0; c2 < ch; ++c2) {
      const int base2 = (b * CH_ + c2) * 4 + h;
      const float cM = ws[OFF_CME + base2 * 2];
      const float cE = ws[OFF_CME + base2 * 2 + 1];
      const float cS = ws[OFF_CS  + base2 * 32 + d];
      const float nM = fmaxf(M, cM);
      const float a1 = __expf(M - nM);
      const float a2 = __expf(cM - nM);
      E = E * a1 + cE * a2;
      S = S * a1 + cS * a2;
      M = nM;
    }
    const int pbeg = ch * CL_;
    for (int p = pbeg; p < pbeg + CL_; ++p) {
      const float v  = preB[p * 4 + h];
      const float ph = phiB[p * 32 + d];
      const float nM = fmaxf(M, v);
      const float al = __expf(M - nM);
      const float w  = __expf(v - nM);
      E = fmaf(E, al, w);
      S = fmaf(S, al, w * ph);
      M = nM;
      sAgg[p - pbeg][tid] = (S / E) * ld_any(mask, b * P_ + p, isf32);
    }
  }
  __syncthreads();

  // ---- phase B: rho(128->64->64) for 32 positions; wave w owns 16 ----
  const int w = tid >> 6;
  const int j = tid & 63;
  const float b1 = ws[OFF_BRHO1 + j];
  const float b2 = ws[OFF_BRHO2 + j];
  const int pbase = b * P_ + ch * CL_;

  for (int g = 0; g < 4; ++g) {
    const int pp = w * 16 + g * 4;
    float a0 = b1, a1 = b1, a2 = b1, a3 = b1;
    const float4* r0 = (const float4*)sAgg[pp + 0];
    const float4* r1 = (const float4*)sAgg[pp + 1];
    const float4* r2 = (const float4*)sAgg[pp + 2];
    const float4* r3 = (const float4*)sAgg[pp + 3];
    #pragma unroll 8
    for (int ii = 0; ii < 32; ++ii) {
      const float4 v0 = r0[ii], v1 = r1[ii], v2 = r2[ii], v3 = r3[ii];
      const float wa = sW1[(4*ii + 0) * 64 + j];
      const float wb = sW1[(4*ii + 1) * 64 + j];
      const float wc = sW1[(4*ii + 2) * 64 + j];
      const float wd = sW1[(4*ii + 3) * 64 + j];
      a0 = fmaf(v0.x, wa, a0); a0 = fmaf(v0.y, wb, a0); a0 = fmaf(v0.z, wc, a0); a0 = fmaf(v0.w, wd, a0);
      a1 = fmaf(v1.x, wa, a1); a1 = fmaf(v1.y, wb, a1); a1 = fmaf(v1.z, wc, a1); a1 = fmaf(v1.w, wd, a1);
      a2 = fmaf(v2.x, wa, a2); a2 = fmaf(v2.y, wb, a2); a2 = fmaf(v2.z, wc, a2); a2 = fmaf(v2.w, wd, a2);
      a3 = fmaf(v3.x, wa, a3); a3 = fmaf(v3.y, wb, a3); a3 = fmaf(v3.z, wc, a3); a3 = fmaf(v3.w, wd, a3);
    }
    // wave-local LDS handoff (same wave writes then reads its own slot)
    sH1[w][0][j] = fmaxf(a0, 0.f);
    sH1[w][1][j] = fmaxf(a1, 0.f);
    sH1[w][2][j] = fmaxf(a2, 0.f);
    sH1[w][3][j] = fmaxf(a3, 0.f);

    float o0 = b2, o1 = b2, o2 = b2, o3 = b2;
    const float4* q0 = (const float4*)sH1[w][0];
    const float4* q1 = (const float4*)sH1[w][1];
    const float4* q2 = (const float4*)sH1[w][2];
    const float4* q3 = (const float4*)sH1[w][3];
    #pragma unroll 4
    for (int ii = 0; ii < 16; ++ii) {
      const float4 u0 = q0[ii], u1 = q1[ii], u2 = q2[ii], u3 = q3[ii];
      const float wa = ws[OFF_WRHO2 + (4*ii + 0) * 64 + j];
      const float wb = ws[OFF_WRHO2 + (4*ii + 1) * 64 + j];
      const float wc = ws[OFF_WRHO2 + (4*ii + 2) * 64 + j];
      const float wd = ws[OFF_WRHO2 + (4*ii + 3) * 64 + j];
      o0 = fmaf(u0.x, wa, o0); o0 = fmaf(u0.y, wb, o0); o0 = fmaf(u0.z, wc, o0); o0 = fmaf(u0.w, wd, o0);
      o1 = fmaf(u1.x, wa, o1); o1 = fmaf(u1.y, wb, o1); o1 = fmaf(u1.z, wc, o1); o1 = fmaf(u1.w, wd, o1);
      o2 = fmaf(u2.x, wa, o2); o2 = fmaf(u2.y, wb, o2); o2 = fmaf(u2.z, wc, o2); o2 = fmaf(u2.w, wd, o2);
      o3 = fmaf(u3.x, wa, o3); o3 = fmaf(u3.y, wb, o3); o3 = fmaf(u3.z, wc, o3); o3 = fmaf(u3.w, wd, o3);
    }

    const float rr[4] = {o0, o1, o2, o3};
    #pragma unroll
    for (int k = 0; k < 4; ++k) {
      const int t = pbase + pp + k;
      const float v = fmaxf(rr[k], 0.f) * ld_any(mask, t, isf32);
      if (isf32) {
        ((float*)out)[(size_t)t * 64 + j] = v;
      } else {
        ((__hip_bfloat16*)out)[(size_t)t * 64 + j] = __float2bfloat16(v);
      }
    }
  }
}

extern "C" void kernel_launch(void* const* d_in, const int* in_sizes, int n_in,
                              void* d_out, int out_size, void* d_ws, size_t ws_size,
                              hipStream_t stream) {
  const int* meas = (const int*)d_in[2];
  const void* times = d_in[0];
  const void* values = d_in[1];
  const void* mask = d_in[3];
  float* ws = (float*)d_ws;

  s01_prep<<<34, 256, 0, stream>>>(ws, mask,
                                   d_in[4], d_in[5], d_in[6], d_in[7],
                                   d_in[8], d_in[9], d_in[10],
                                   d_in[11], d_in[12], d_in[13], d_in[14],
                                   d_in[15], d_in[16], d_in[17], d_in[18]);
  k1_token<<<T_/4, 256, 0, stream>>>(ws, meas, times, values, mask);
  k2_scanz<<<B_, 256, 0, stream>>>(ws, mask);
  k4a_chunk<<<dim3(CH_, B_), 128, 0, stream>>>(ws);
  k4r_fused<<<dim3(CH_, B_), 128, 0, stream>>>(ws, mask, d_out);
}

// Round 8
// 159.852 us; speedup vs baseline: 1.0456x; 1.0456x over previous
//
#include <hip/hip_runtime.h>
#include <hip/hip_bf16.h>

#define B_ 16
#define P_ 1024
#define T_ (B_*P_)
#define CH_ 32          // chunks per batch for the softmax scan
#define CL_ (P_/CH_)    // 32 positions per chunk

// ---- ws layout (floats). Weights staged to f32; token inputs read raw. ----
constexpr int OFF_A     = 16;                       // 95*4 + 4 = 384
constexpr int OFF_WPSI1 = 400;                      // 1984
constexpr int OFF_BPSI1 = OFF_WPSI1 + 1984;         // 64
constexpr int OFF_WPSI2 = OFF_BPSI1 + 64;           // 4096
constexpr int OFF_BPSI2 = OFF_WPSI2 + 4096;         // 64
constexpr int OFF_WPHI1 = OFF_BPSI2 + 64;           // 992
constexpr int OFF_BPHI1 = OFF_WPHI1 + 992;          // 32
constexpr int OFF_WPHI2 = OFF_BPHI1 + 32;           // 1024
constexpr int OFF_BPHI2 = OFF_WPHI2 + 1024;         // 32
constexpr int OFF_WRHO1 = OFF_BPHI2 + 32;           // 8192
constexpr int OFF_BRHO1 = OFF_WRHO1 + 8192;         // 64
constexpr int OFF_WRHO2 = OFF_BRHO1 + 64;           // 4096
constexpr int OFF_BRHO2 = OFF_WRHO2 + 4096;         // 64
constexpr int OFF_PHI   = OFF_BRHO2 + 64;           // T*32  phi*mask
constexpr int OFF_Z     = OFF_PHI   + T_*32;        // T*4   z = (psi*m).A2
constexpr int OFF_PREX  = OFF_Z     + T_*4;         // T*4
constexpr int OFF_EXPW  = OFF_PREX  + T_*4;         // T*4   e = exp(pre - M[b,h])
constexpr int OFF_CE    = OFF_EXPW  + T_*4;         // B*CH*4 = 2048 chunk E-sums
constexpr int OFF_CS    = OFF_CE    + 2048;         // B*CH*128 = 65536 chunk S-sums
constexpr int OFF_AGG   = OFF_CS    + 65536;        // T*128

static __device__ __forceinline__ bool detect_f32(const void* mask_raw) {
  return ((*(const unsigned*)mask_raw) & 0xFFFFu) == 0u;
}
static __device__ __forceinline__ float ld_any(const void* src, int i, bool isf32) {
  if (isf32) return ((const float*)src)[i];
  return __bfloat162float(((const __hip_bfloat16*)src)[i]);
}

// ---------- S01: stage weights to f32 (blocks >=2) + fold A (blocks 0..1) ----------
__global__ __launch_bounds__(256) void s01_prep(
    float* __restrict__ ws, const void* mask,
    const void* Wpsi1, const void* bpsi1, const void* Wpsi2, const void* bpsi2,
    const void* Wkey,  const void* bkey,  const void* query,
    const void* Wphi1, const void* bphi1, const void* Wphi2, const void* bphi2,
    const void* Wrho1, const void* brho1, const void* Wrho2, const void* brho2) {
  const bool isf32 = detect_f32(mask);
  if (blockIdx.x < 2) {
    const int gid = blockIdx.x * 256 + threadIdx.x;
    if (gid >= 384) return;
    const float inv_s = 0.17677669529663687f;
    const int h = gid & 3;
    const int j = gid >> 2;  // 0..95; 95 = bias row
    float s = 0.f;
    if (j < 95) {
      for (int d = 0; d < 32; ++d)
        s += ld_any(Wkey, j * 128 + h * 32 + d, isf32) * ld_any(query, h * 32 + d, isf32);
    } else {
      for (int d = 0; d < 32; ++d)
        s += ld_any(bkey, h * 32 + d, isf32) * ld_any(query, h * 32 + d, isf32);
    }
    ws[OFF_A + gid] = s * inv_s;  // A[j][h] at j*4+h; c0[h] at 380+h
    return;
  }
  const int g  = (blockIdx.x - 2) * 256 + threadIdx.x;
  const int gs = (gridDim.x - 2) * 256;
  auto st = [&](int off, const void* src, int n) {
    for (int i = g; i < n; i += gs) ws[off + i] = ld_any(src, i, isf32);
  };
  st(OFF_WPSI1, Wpsi1, 1984); st(OFF_BPSI1, bpsi1, 64);
  st(OFF_WPSI2, Wpsi2, 4096); st(OFF_BPSI2, bpsi2, 64);
  st(OFF_WPHI1, Wphi1, 992);  st(OFF_BPHI1, bphi1, 32);
  st(OFF_WPHI2, Wphi2, 1024); st(OFF_BPHI2, bphi2, 32);
  st(OFF_WRHO1, Wrho1, 8192); st(OFF_BRHO1, brho1, 64);
  st(OFF_WRHO2, Wrho2, 4096); st(OFF_BRHO2, brho2, 64);
}

// ---------- K1: wave-per-token MLPs. 4 tokens/block, lane=channel ----------
__global__ __launch_bounds__(256) void k1_token(float* __restrict__ ws,
                                                const int* __restrict__ measp,
                                                const void* __restrict__ times,
                                                const void* __restrict__ values,
                                                const void* __restrict__ mask) {
  __shared__ float sh1[4][64];
  __shared__ float sg1[4][32];
  const bool isf32 = detect_f32(mask);
  const int tid = threadIdx.x;
  const int wv  = __builtin_amdgcn_readfirstlane(tid >> 6);
  const int j   = tid & 63;
  const int t   = blockIdx.x * 4 + wv;

  const float tval = ld_any(times, t, isf32);
  const float vval = ld_any(values, t, isf32);
  const float mval = ld_any(mask, t, isf32);
  const int   meas = measp[t];
  const float sel  = (meas > 0) ? 1.f : 0.f;
  const int   mrow = (meas > 0) ? (8 + meas) : 0;

  float x[9];
  const float posv[4] = {1.f, 10.f, 100.f, 1000.f};
  #pragma unroll
  for (int k = 0; k < 4; ++k) {
    float s, c;
    __sincosf(tval / posv[k], &s, &c);
    x[2*k] = s; x[2*k+1] = c;
  }
  x[8] = vval;

  // psi L1, channel j
  float h1 = ws[OFF_BPSI1 + j];
  #pragma unroll
  for (int i = 0; i < 9; ++i) h1 = fmaf(x[i], ws[OFF_WPSI1 + i * 64 + j], h1);
  h1 = fmaf(sel, ws[OFF_WPSI1 + mrow * 64 + j], h1);
  sh1[wv][j] = fmaxf(h1, 0.f);

  // phi L1, lanes 0..31
  if (j < 32) {
    float g1 = ws[OFF_BPHI1 + j];
    #pragma unroll
    for (int i = 0; i < 9; ++i) g1 = fmaf(x[i], ws[OFF_WPHI1 + i * 32 + j], g1);
    g1 = fmaf(sel, ws[OFF_WPHI1 + mrow * 32 + j], g1);
    sg1[wv][j] = fmaxf(g1, 0.f);
  }
  __syncthreads();

  // psi L2
  float h2 = ws[OFF_BPSI2 + j];
  #pragma unroll 8
  for (int i = 0; i < 64; ++i) h2 = fmaf(sh1[wv][i], ws[OFF_WPSI2 + i * 64 + j], h2);
  const float q = fmaxf(h2, 0.f) * mval;

  // z[h] = sum_j q_j * A2[j][h] — butterfly over the wave
  const float* a2 = ws + OFF_A + (31 + j) * 4;
  float z0 = q * a2[0], z1 = q * a2[1], z2 = q * a2[2], z3 = q * a2[3];
  #pragma unroll
  for (int off = 32; off; off >>= 1) {
    z0 += __shfl_xor(z0, off, 64);
    z1 += __shfl_xor(z1, off, 64);
    z2 += __shfl_xor(z2, off, 64);
    z3 += __shfl_xor(z3, off, 64);
  }
  if (j == 0) {
    float* zo = ws + OFF_Z + (size_t)t * 4;
    zo[0] = z0; zo[1] = z1; zo[2] = z2; zo[3] = z3;
  }

  // phi L2 on lanes 0..31; pre_x on lanes 32..35
  if (j < 32) {
    float g2 = ws[OFF_BPHI2 + j];
    #pragma unroll 8
    for (int i = 0; i < 32; ++i) g2 = fmaf(sg1[wv][i], ws[OFF_WPHI2 + i * 32 + j], g2);
    ws[OFF_PHI + (size_t)t * 32 + j] = fmaxf(g2, 0.f) * mval;
  } else if (j < 36) {
    const int h = j - 32;
    float pr = ws[OFF_A + 380 + h];
    #pragma unroll
    for (int i = 0; i < 9; ++i) pr = fmaf(x[i], ws[OFF_A + i * 4 + h], pr);
    pr = fmaf(sel, ws[OFF_A + mrow * 4 + h], pr);
    ws[OFF_PREX + (size_t)t * 4 + h] = pr;
  }
}

// ---------- K2: scan (cnt, z[4]) -> pre; batch-max per head; e = exp(pre-M) ----------
// one block per batch; 256 threads x 4 consecutive positions each
__global__ __launch_bounds__(256) void k2_scanz(float* __restrict__ ws,
                                                const void* __restrict__ mask) {
  const int b   = blockIdx.x;
  const int tid = threadIdx.x;
  const bool isf32 = detect_f32(mask);
  __shared__ float sc[256], s0[256], s1[256], s2[256], s3[256];

  const float* zB = ws + OFF_Z + (size_t)b * P_ * 4;
  const int p0 = tid * 4;

  float lc[4], l0[4], l1[4], l2[4], l3[4];
  float c = 0.f, z0 = 0.f, z1 = 0.f, z2 = 0.f, z3 = 0.f;
  #pragma unroll
  for (int i = 0; i < 4; ++i) {
    c  += ld_any(mask, b * P_ + p0 + i, isf32);
    z0 += zB[(p0 + i) * 4 + 0]; z1 += zB[(p0 + i) * 4 + 1];
    z2 += zB[(p0 + i) * 4 + 2]; z3 += zB[(p0 + i) * 4 + 3];
    lc[i] = c; l0[i] = z0; l1[i] = z1; l2[i] = z2; l3[i] = z3;
  }

  float rc = c, r0 = z0, r1 = z1, r2 = z2, r3 = z3;
  sc[tid] = rc; s0[tid] = r0; s1[tid] = r1; s2[tid] = r2; s3[tid] = r3;
  __syncthreads();
  for (int off = 1; off < 256; off <<= 1) {
    float ac = 0.f, a0 = 0.f, a1 = 0.f, a2 = 0.f, a3 = 0.f;
    if (tid >= off) {
      ac = sc[tid - off]; a0 = s0[tid - off]; a1 = s1[tid - off];
      a2 = s2[tid - off]; a3 = s3[tid - off];
    }
    __syncthreads();
    rc += ac; r0 += a0; r1 += a1; r2 += a2; r3 += a3;
    sc[tid] = rc; s0[tid] = r0; s1[tid] = r1; s2[tid] = r2; s3[tid] = r3;
    __syncthreads();
  }
  const float ec = rc - c, e0 = r0 - z0, e1 = r1 - z1, e2 = r2 - z2, e3 = r3 - z3;

  // pre for this thread's 4 positions x 4 heads
  const float* px = ws + OFF_PREX + (size_t)b * P_ * 4;
  float pre[4][4];
  float mx0 = -1e30f, mx1 = -1e30f, mx2 = -1e30f, mx3 = -1e30f;
  #pragma unroll
  for (int i = 0; i < 4; ++i) {
    const float inv = 1.f / (ec + lc[i]);
    const int p = p0 + i;
    pre[i][0] = px[p * 4 + 0] + (e0 + l0[i]) * inv;
    pre[i][1] = px[p * 4 + 1] + (e1 + l1[i]) * inv;
    pre[i][2] = px[p * 4 + 2] + (e2 + l2[i]) * inv;
    pre[i][3] = px[p * 4 + 3] + (e3 + l3[i]) * inv;
    mx0 = fmaxf(mx0, pre[i][0]); mx1 = fmaxf(mx1, pre[i][1]);
    mx2 = fmaxf(mx2, pre[i][2]); mx3 = fmaxf(mx3, pre[i][3]);
  }

  // block-wide max per head (reuse scan arrays)
  __syncthreads();
  s0[tid] = mx0; s1[tid] = mx1; s2[tid] = mx2; s3[tid] = mx3;
  __syncthreads();
  for (int off = 128; off; off >>= 1) {
    if (tid < off) {
      s0[tid] = fmaxf(s0[tid], s0[tid + off]);
      s1[tid] = fmaxf(s1[tid], s1[tid + off]);
      s2[tid] = fmaxf(s2[tid], s2[tid + off]);
      s3[tid] = fmaxf(s3[tid], s3[tid + off]);
    }
    __syncthreads();
  }
  const float M0 = s0[0], M1 = s1[0], M2 = s2[0], M3 = s3[0];

  // e = exp(pre - M)  (16 independent exps)
  float* eB = ws + OFF_EXPW + (size_t)b * P_ * 4;
  #pragma unroll
  for (int i = 0; i < 4; ++i) {
    const int p = p0 + i;
    eB[p * 4 + 0] = __expf(pre[i][0] - M0);
    eB[p * 4 + 1] = __expf(pre[i][1] - M1);
    eB[p * 4 + 2] = __expf(pre[i][2] - M2);
    eB[p * 4 + 3] = __expf(pre[i][3] - M3);
  }
}

// ---------- K4a: per-chunk plain sums of (e, e*phi) ----------
// grid (CH_, B_), block 128: h = tid>>5, d = tid&31
__global__ __launch_bounds__(128) void k4a_sums(float* __restrict__ ws) {
  const int ch = blockIdx.x, b = blockIdx.y;
  const int h = threadIdx.x >> 5, d = threadIdx.x & 31;
  const float* eB   = ws + OFF_EXPW + (size_t)b * P_ * 4;
  const float* phiB = ws + OFF_PHI  + (size_t)b * P_ * 32;

  float E = 0.f, S = 0.f;
  const int pbeg = ch * CL_;
  #pragma unroll 4
  for (int p = pbeg; p < pbeg + CL_; ++p) {
    const float e  = eB[p * 4 + h];
    const float ph = phiB[p * 32 + d];
    E += e;
    S = fmaf(e, ph, S);
  }
  const int base = (b * CH_ + ch) * 4 + h;
  if (d == 0) ws[OFF_CE + base] = E;
  ws[OFF_CS + base * 32 + d] = S;
}

// ---------- K4c: prefix (pure adds) + replay chunk, write agg ----------
__global__ __launch_bounds__(128) void k4c_replay(float* __restrict__ ws,
                                                  const void* __restrict__ mask) {
  const int ch = blockIdx.x, b = blockIdx.y;
  const int h = threadIdx.x >> 5, d = threadIdx.x & 31;
  const bool isf32 = detect_f32(mask);
  const float* eB   = ws + OFF_EXPW + (size_t)b * P_ * 4;
  const float* phiB = ws + OFF_PHI  + (size_t)b * P_ * 32;
  float*       aggB = ws + OFF_AGG  + (size_t)b * P_ * 128;

  float E = 0.f, S = 0.f;
  for (int c2 = 0; c2 < ch; ++c2) {
    const int base2 = (b * CH_ + c2) * 4 + h;
    E += ws[OFF_CE + base2];
    S += ws[OFF_CS + base2 * 32 + d];
  }

  const int pbeg = ch * CL_;
  for (int p = pbeg; p < pbeg + CL_; ++p) {
    const float e  = eB[p * 4 + h];
    const float ph = phiB[p * 32 + d];
    E += e;
    S = fmaf(e, ph, S);
    aggB[p * 128 + h * 32 + d] = (S / E) * ld_any(mask, b * P_ + p, isf32);
  }
}

// ---------- K5: rho MLP, 16 tokens/block, 4 tokens/wave, lane=channel ----------
__global__ __launch_bounds__(256) void k5_rho(const float* __restrict__ ws,
                                              const void* __restrict__ mask_raw,
                                              void* __restrict__ out) {
  __shared__ float sW1[128 * 64];   // 32 KB
  __shared__ float sH1[16][64];     // 4 KB
  const int tid = threadIdx.x;
  for (int i = tid; i < 128 * 64; i += 256) sW1[i] = ws[OFF_WRHO1 + i];

  const int wv = __builtin_amdgcn_readfirstlane(tid >> 6);
  const int j  = tid & 63;
  const int t0 = blockIdx.x * 16 + wv * 4;
  const float* aggB = ws + OFF_AGG;

  const float b1 = ws[OFF_BRHO1 + j];
  float a0 = b1, a1 = b1, a2 = b1, a3 = b1;
  __syncthreads();

  #pragma unroll 8
  for (int i = 0; i < 128; ++i) {
    const float w = sW1[i * 64 + j];
    a0 = fmaf(aggB[(size_t)(t0 + 0) * 128 + i], w, a0);
    a1 = fmaf(aggB[(size_t)(t0 + 1) * 128 + i], w, a1);
    a2 = fmaf(aggB[(size_t)(t0 + 2) * 128 + i], w, a2);
    a3 = fmaf(aggB[(size_t)(t0 + 3) * 128 + i], w, a3);
  }
  sH1[wv * 4 + 0][j] = fmaxf(a0, 0.f);
  sH1[wv * 4 + 1][j] = fmaxf(a1, 0.f);
  sH1[wv * 4 + 2][j] = fmaxf(a2, 0.f);
  sH1[wv * 4 + 3][j] = fmaxf(a3, 0.f);
  __syncthreads();

  const float b2 = ws[OFF_BRHO2 + j];
  float o0 = b2, o1 = b2, o2 = b2, o3 = b2;
  #pragma unroll 8
  for (int i = 0; i < 64; ++i) {
    const float w = ws[OFF_WRHO2 + i * 64 + j];
    o0 = fmaf(sH1[wv * 4 + 0][i], w, o0);
    o1 = fmaf(sH1[wv * 4 + 1][i], w, o1);
    o2 = fmaf(sH1[wv * 4 + 2][i], w, o2);
    o3 = fmaf(sH1[wv * 4 + 3][i], w, o3);
  }

  const bool isf32 = detect_f32(mask_raw);
  float r[4] = {o0, o1, o2, o3};
  #pragma unroll
  for (int k = 0; k < 4; ++k) {
    const int t = t0 + k;
    const float v = fmaxf(r[k], 0.f) * ld_any(mask_raw, t, isf32);
    if (isf32) {
      ((float*)out)[(size_t)t * 64 + j] = v;
    } else {
      ((__hip_bfloat16*)out)[(size_t)t * 64 + j] = __float2bfloat16(v);
    }
  }
}

extern "C" void kernel_launch(void* const* d_in, const int* in_sizes, int n_in,
                              void* d_out, int out_size, void* d_ws, size_t ws_size,
                              hipStream_t stream) {
  const int* meas = (const int*)d_in[2];
  const void* times = d_in[0];
  const void* values = d_in[1];
  const void* mask = d_in[3];
  float* ws = (float*)d_ws;

  s01_prep<<<34, 256, 0, stream>>>(ws, mask,
                                   d_in[4], d_in[5], d_in[6], d_in[7],
                                   d_in[8], d_in[9], d_in[10],
                                   d_in[11], d_in[12], d_in[13], d_in[14],
                                   d_in[15], d_in[16], d_in[17], d_in[18]);
  k1_token<<<T_/4, 256, 0, stream>>>(ws, meas, times, values, mask);
  k2_scanz<<<B_, 256, 0, stream>>>(ws, mask);
  k4a_sums<<<dim3(CH_, B_), 128, 0, stream>>>(ws);
  k4c_replay<<<dim3(CH_, B_), 128, 0, stream>>>(ws, mask);
  k5_rho<<<T_/16, 256, 0, stream>>>(ws, mask, d_out);
}